// Round 10
// baseline (241.362 us; speedup 1.0000x reference)
//
#include <hip/hip_runtime.h>

#define M1      33                  // LPC_ORDER + 1
#define TROWS   64                  // rows per tile (one wave, 1 row/thread)
#define TILE_F  (TROWS * M1)        // 2112 floats = 8448 B per tile
#define TILE_V4 528                 // float4 per tile
#define BLK     256                 // 4 waves per workgroup
#define WPB     4                   // waves per block (private LDS slice each; NO barriers)
#define PARTIAL 16                  // lanes active in the 9th chunk (528 = 8*64 + 16)
#define GRID    1024                // 4 WG/CU x 256 CU; 4096 waves -> 4 tiles/wave

// Pinned depth-1 register-prefetch pipeline, 4 independent waves/WG.
//
// Ledger through round 9: six schedules (4-phase barrier, global_load_lds
// dbuf, nt-stores, reg dbuf, depth-2 reg prefetch) ALL tie at 83-93 us /
// ~2.45 TB/s, traffic byte-identical, no pipe >20%. Round 9's VGPR_Count=88
// (vs ~125 required for two live prefetch sets) proves the compiler SANK the
// prefetch loads to just before their LDS-stage use, re-serializing every
// source-level pipeline. Occupancy is a dead lever (37% r0 == 17% r9 perf).
//
// Fix: __builtin_amdgcn_sched_barrier(0) immediately after the load issue --
// a compile-time fence nothing may cross -- so the loads CANNOT sink below
// the compute phase. Their counted vmcnt wait then lands at the next
// iteration's STAGESET, ~1500 cycles of Levinson compute later. Loads may
// still hoist earlier (good), never later. The 9th (partial) chunk becomes a
// full-wave load with the address clamped to the tile's last float4 (lanes
// >=16 dup-read in-bounds data; only lanes <16 are staged/stored) so the
// whole tile is 9 unconditional VMEM ops.
// Verification signal: VGPR ~95-115 (prefetch set live across compute).
__global__ __launch_bounds__(BLK, 2)
void parcor_to_lpc_kernel(const float* __restrict__ k, float* __restrict__ out,
                          int ntiles) {
    __shared__ __align__(16) float lds_all[WPB * TILE_F];   // 33,792 B -> 4 WG/CU
    const int lane = threadIdx.x & 63;
    const int wid  = threadIdx.x >> 6;
    float* const lds = lds_all + wid * TILE_F;              // private per-wave slice

    const int nw  = gridDim.x * WPB;                        // total waves
    const int gw  = blockIdx.x * WPB + wid;                 // global wave id
    const int tpw = (ntiles + nw - 1) / nw;                 // tiles per wave
    int t         = gw * tpw;                               // contiguous tile range
    const int t1  = (t + tpw < ntiles) ? t + tpw : ntiles;
    if (t >= t1) return;

    // clamped index for the 9th chunk: full-wave, always in-bounds
    const int i9 = 8 * TROWS + (lane < PARTIAL ? lane : PARTIAL - 1);

    float4 R0, R1, R2, R3, R4, R5, R6, R7, R8;              // 36-VGPR prefetch set

#define LOADSET(tidx) do {                                              \
        const float4* g4_ = (const float4*)(k + (size_t)(tidx) * TILE_F); \
        R0 = g4_[0 * TROWS + lane];  R1 = g4_[1 * TROWS + lane];        \
        R2 = g4_[2 * TROWS + lane];  R3 = g4_[3 * TROWS + lane];        \
        R4 = g4_[4 * TROWS + lane];  R5 = g4_[5 * TROWS + lane];        \
        R6 = g4_[6 * TROWS + lane];  R7 = g4_[7 * TROWS + lane];        \
        R8 = g4_[i9];                                                   \
    } while (0)

#define STAGESET() do {                                                 \
        float4* l4_ = (float4*)lds;                                     \
        l4_[0 * TROWS + lane] = R0;  l4_[1 * TROWS + lane] = R1;        \
        l4_[2 * TROWS + lane] = R2;  l4_[3 * TROWS + lane] = R3;        \
        l4_[4 * TROWS + lane] = R4;  l4_[5 * TROWS + lane] = R5;        \
        l4_[6 * TROWS + lane] = R6;  l4_[7 * TROWS + lane] = R7;        \
        if (lane < PARTIAL) l4_[8 * TROWS + lane] = R8;                 \
    } while (0)

    // ---- prologue: first tile into regs ----
    LOADSET(t);

    while (true) {
        // Stage current tile regs -> LDS. The compiler's counted vmcnt wait
        // for this set's loads lands here -- one full compute phase old.
        STAGESET();

        // Issue NEXT tile's 9 loads, then fence: sched_barrier(0) forbids
        // sinking them below the compute that follows.
        const int tn = t + 1;
        if (tn < t1) {
            LOADSET(tn);
            __builtin_amdgcn_sched_barrier(0);
        }

        // Own-wave ds_writes visible to cross-lane row reads (per-wave
        // lgkmcnt; no barrier anywhere => no vmcnt drain).
        asm volatile("s_waitcnt lgkmcnt(0)" ::: "memory");

        // LDS -> regs: row stride 33 floats => bank (lane+j)%32; 2-way
        // aliasing across wave64 = conflict-free.
        float a[M1];
        #pragma unroll
        for (int j = 0; j < M1; ++j) a[j] = lds[lane * M1 + j];

        // Levinson step-up recursion, fully unrolled, in registers.
        #pragma unroll
        for (int m = 2; m < M1; ++m) {
            const float km = a[m];
            #pragma unroll
            for (int j = 1; 2 * j < m; ++j) {
                const float x = a[j];
                const float y = a[m - j];
                a[j]     = fmaf(km, y, x);
                a[m - j] = fmaf(km, x, y);
            }
            if ((m & 1) == 0) {
                const int jh = m >> 1;
                a[jh] = fmaf(km, a[jh], a[jh]);   // midpoint: a[j]*(1+km)
            }
        }

        // regs -> LDS (own row), then cross-lane coalesced store.
        #pragma unroll
        for (int j = 0; j < M1; ++j) lds[lane * M1 + j] = a[j];
        asm volatile("s_waitcnt lgkmcnt(0)" ::: "memory");

        {
            const float4* l4 = (const float4*)lds;
            float4* g4o = (float4*)(out + (size_t)t * TILE_F);
            #pragma unroll
            for (int i = 0; i < 8; ++i)
                g4o[i * TROWS + lane] = l4[i * TROWS + lane];
            if (lane < PARTIAL)
                g4o[8 * TROWS + lane] = l4[8 * TROWS + lane];
        }

        if (tn >= t1) break;
        t = tn;
    }
#undef LOADSET
#undef STAGESET
}

// Fallback for trailing rows (nrows % 64 != 0) -- not hit for 16x65536.
__global__ void parcor_to_lpc_tail_kernel(const float* __restrict__ k,
                                          float* __restrict__ out,
                                          int row_start, int nrows) {
    const int row = row_start + blockIdx.x * blockDim.x + threadIdx.x;
    if (row >= nrows) return;
    const float* src = k + (size_t)row * M1;
    float* dst = out + (size_t)row * M1;
    float a[M1];
    #pragma unroll
    for (int j = 0; j < M1; ++j) a[j] = src[j];
    #pragma unroll
    for (int m = 2; m < M1; ++m) {
        const float km = a[m];
        #pragma unroll
        for (int j = 1; 2 * j < m; ++j) {
            const float x = a[j];
            const float y = a[m - j];
            a[j]     = fmaf(km, y, x);
            a[m - j] = fmaf(km, x, y);
        }
        if ((m & 1) == 0) {
            const int j = m >> 1;
            a[j] = fmaf(km, a[j], a[j]);
        }
    }
    #pragma unroll
    for (int j = 0; j < M1; ++j) dst[j] = a[j];
}

extern "C" void kernel_launch(void* const* d_in, const int* in_sizes, int n_in,
                              void* d_out, int out_size, void* d_ws, size_t ws_size,
                              hipStream_t stream) {
    const float* k = (const float*)d_in[0];
    float* out = (float*)d_out;

    const int nrows     = in_sizes[0] / M1;    // 16 * 65536 = 1,048,576
    const int ntiles    = nrows / TROWS;       // 16384 tiles
    const int tile_rows = ntiles * TROWS;
    const int rem       = nrows - tile_rows;

    if (ntiles > 0) {
        const int grid = (ntiles + WPB - 1) / WPB < GRID
                       ? (ntiles + WPB - 1) / WPB : GRID;
        parcor_to_lpc_kernel<<<grid, BLK, 0, stream>>>(k, out, ntiles);
    }
    if (rem > 0)
        parcor_to_lpc_tail_kernel<<<(rem + 63) / 64, 64, 0, stream>>>(
            k, out, tile_rows, nrows);
}